// Round 11
// baseline (288.794 us; speedup 1.0000x reference)
//
#include <hip/hip_runtime.h>
#include <cstddef>
#include <cstdint>

#define SEQ 2048
#define DM 1024
#define NH 16
#define HD 64

typedef _Float16 f16;
typedef __attribute__((ext_vector_type(8))) _Float16 f16x8;
typedef __attribute__((ext_vector_type(4))) _Float16 f16x4;
typedef __attribute__((ext_vector_type(2))) _Float16 f16x2;
typedef __attribute__((ext_vector_type(4))) float f32x4;

// one launch: cast x (1M float4) + 4 weights (256K float4 each) into the
// contiguous 16 MB f16 region [xb | Wq | Wk | Wv | Wo]
__global__ __launch_bounds__(256) void cast_all(const float* __restrict__ x,
                                                const float* __restrict__ Wq,
                                                const float* __restrict__ Wk,
                                                const float* __restrict__ Wv,
                                                const float* __restrict__ Wo,
                                                f16* __restrict__ dst) {
  const int i = blockIdx.x * 256 + threadIdx.x;  // float4 index, 2M total
  const float* src;
  int off;
  if (i < 1048576) {
    src = x; off = i;
  } else {
    const int j = i - 1048576;
    const int wsel = j >> 18;
    src = (wsel == 0) ? Wq : (wsel == 1) ? Wk : (wsel == 2) ? Wv : Wo;
    off = j & 262143;
  }
  const float4 v = ((const float4*)src)[off];
  f16x4 o = {(f16)v.x, (f16)v.y, (f16)v.z, (f16)v.w};
  ((f16x4*)dst)[i] = o;
}

__device__ __forceinline__ void gload16(const void* g, void* lds) {
  __builtin_amdgcn_global_load_lds((const __attribute__((address_space(1))) void*)g,
                                   (__attribute__((address_space(3))) void*)lds,
                                   16, 0, 0);
}

// ---------------------------------------------------------------------------
// f16 GEMM mainloop (m97 structure), 128x128 tile.
// ---------------------------------------------------------------------------
__device__ __forceinline__ void gemm_tile(const f16* __restrict__ A,
                                          const f16* __restrict__ B,
                                          f16* As, f16* Bs,
                                          int K, f32x4 acc[4][4]) {
  const int t = threadIdx.x;
  const int lane = t & 63;
  const int w = t >> 6;
  const int wm = (w & 1) << 6, wn = (w >> 1) << 6;
  const int srow = lane >> 2, scol = lane & 3;
  const int fr = lane & 15, q = lane >> 4;
  for (int k0 = 0; k0 < K; k0 += 32) {
    __syncthreads();
#pragma unroll
    for (int c = 0; c < 2; ++c) {
      const int chunk = (w << 1) + c;
      const int row = (chunk << 4) + srow;
      gload16(A + (size_t)row * K + k0 + (scol << 3), As + (chunk << 9));
      gload16(B + (size_t)row * K + k0 + (scol << 3), Bs + (chunk << 9));
    }
    __syncthreads();
    f16x8 af[4], bfr[4];
#pragma unroll
    for (int i = 0; i < 4; ++i)
      af[i] = *(const f16x8*)(As + (wm + (i << 4) + fr) * 32 + (q << 3));
#pragma unroll
    for (int j = 0; j < 4; ++j)
      bfr[j] = *(const f16x8*)(Bs + (wn + (j << 4) + fr) * 32 + (q << 3));
#pragma unroll
    for (int i = 0; i < 4; ++i)
#pragma unroll
      for (int j = 0; j < 4; ++j)
        acc[i][j] = __builtin_amdgcn_mfma_f32_16x16x32_f16(af[i], bfr[j],
                                                           acc[i][j], 0, 0, 0);
  }
}

// Fused QKV projection. Q pre-scaled by log2(e)/sqrt(d_model).
// Q/K epilogue via LDS transpose -> coalesced f16x8 stores; V epilogue:
// direct frag-layout f16x4 stores.
//   Vtg flat(d,s) = bh*131072 + (s>>6)*4096 + ((s>>2)&15)*256 + d*4 + (s&3)
#define QSCALE 0.04508422003f /* 1.4426950409/32 */
__global__ __launch_bounds__(256) void gemm_qkv(
    const f16* __restrict__ xb, const f16* __restrict__ Wqb,
    const f16* __restrict__ Wkb, const f16* __restrict__ Wvb,
    f16* __restrict__ Qb, f16* __restrict__ Kb, f16* __restrict__ Vtg) {
  __shared__ f16 smem[16896];
  f16* As = smem;
  f16* Bs = smem + 4096;
  const int which = blockIdx.x >> 3;
  const int bn = (blockIdx.x & 7) << 7;
  const int bm = blockIdx.y << 7;
  const f16* B = (which == 0) ? Wqb : (which == 1) ? Wkb : Wvb;
  f32x4 acc[4][4] = {};
  gemm_tile(xb + (size_t)bm * DM, B + (size_t)bn * DM, As, Bs, DM, acc);
  const int t = threadIdx.x;
  const int lane = t & 63, w = t >> 6;
  const int wm = (w & 1) << 6, wn = (w >> 1) << 6;
  const int col = lane & 15, q = lane >> 4;
  if (which < 2) {
    f16* C = (which == 0) ? Qb : Kb;
    const float sc = (which == 0) ? QSCALE : 1.0f;
    __syncthreads();
#pragma unroll
    for (int i = 0; i < 4; ++i) {
      const int m0 = wm + (i << 4) + (q << 2);
#pragma unroll
      for (int j = 0; j < 4; ++j) {
        const int n = wn + (j << 4) + col;
#pragma unroll
        for (int r = 0; r < 4; ++r)
          smem[(m0 + r) * 132 + n] = (f16)(acc[i][j][r] * sc);
      }
    }
    __syncthreads();
#pragma unroll
    for (int p = 0; p < 8; ++p) {
      const int idx = t + (p << 8);
      const int row = idx >> 4, c8 = (idx & 15) << 3;
      const f16x8 v = *(const f16x8*)(smem + row * 132 + c8);
      *(f16x8*)(C + (size_t)(bm + row) * DM + bn + c8) = v;
    }
  } else {
    const int b = bm >> 11, sb = bm & 2047;
#pragma unroll
    for (int i = 0; i < 4; ++i) {
      const int sg = sb + wm + (i << 4) + (q << 2);
#pragma unroll
      for (int j = 0; j < 4; ++j) {
        const int n = bn + wn + (j << 4) + col;
        const int bh = (b << 4) + (n >> 6), d = n & 63;
        f16x4 o = {(f16)acc[i][j][0], (f16)acc[i][j][1],
                   (f16)acc[i][j][2], (f16)acc[i][j][3]};
        const size_t flat = ((size_t)bh << 17) + ((size_t)(sg >> 6) << 12) +
                            (((sg >> 2) & 15) << 8) + (d << 2);
        *(f16x4*)(Vtg + flat) = o;
      }
    }
  }
}

// R11: 128(M)x64(N) tile -> grid 512 = 2 blocks/CU (was 256 = 1/CU).
__global__ __launch_bounds__(256) void gemm_out(const f16* __restrict__ Ab,
                                                const f16* __restrict__ Wob,
                                                float* __restrict__ out) {
  __shared__ f16 As[4096];  // 128 x 32
  __shared__ f16 Bs[2048];  // 64 x 32
  const int bn = blockIdx.x << 6, bm = blockIdx.y << 7;
  const int t = threadIdx.x, lane = t & 63, w = t >> 6;
  const int wm = (w & 1) << 6, wn = (w >> 1) << 5;
  const int srow = lane >> 2, scol = lane & 3;
  const int fr = lane & 15, q = lane >> 4;
  f32x4 acc[4][2] = {};
  for (int k0 = 0; k0 < DM; k0 += 32) {
    __syncthreads();
#pragma unroll
    for (int c = 0; c < 2; ++c) {
      const int chunk = (w << 1) + c;
      const int row = (chunk << 4) + srow;
      gload16(Ab + (size_t)(bm + row) * DM + k0 + (scol << 3), As + (chunk << 9));
    }
    {
      const int row = (w << 4) + srow;
      gload16(Wob + (size_t)(bn + row) * DM + k0 + (scol << 3), Bs + (w << 9));
    }
    __syncthreads();
    f16x8 af[4], bfr[2];
#pragma unroll
    for (int i = 0; i < 4; ++i)
      af[i] = *(const f16x8*)(As + (wm + (i << 4) + fr) * 32 + (q << 3));
#pragma unroll
    for (int j = 0; j < 2; ++j)
      bfr[j] = *(const f16x8*)(Bs + (wn + (j << 4) + fr) * 32 + (q << 3));
#pragma unroll
    for (int i = 0; i < 4; ++i)
#pragma unroll
      for (int j = 0; j < 2; ++j)
        acc[i][j] = __builtin_amdgcn_mfma_f32_16x16x32_f16(af[i], bfr[j],
                                                           acc[i][j], 0, 0, 0);
  }
  const int col = lane & 15;
#pragma unroll
  for (int i = 0; i < 4; ++i) {
    const int m = bm + wm + (i << 4) + (q << 2);
#pragma unroll
    for (int j = 0; j < 2; ++j) {
      const int n = bn + wn + (j << 4) + col;
#pragma unroll
      for (int r = 0; r < 4; ++r)
        out[(size_t)(m + r) * DM + n] = acc[i][j][r];
    }
  }
}

// ---------------------------------------------------------------------------
// MFMA flash attention R11: q-tile 64 -> grid 1024 = 4 blocks/CU (was 2).
// Wave owns one 16-q tile. K-staging + V-register pipeline unchanged (R9).
// ---------------------------------------------------------------------------
__global__ __launch_bounds__(256, 4) void attn_mfma(const f16* __restrict__ Qb,
                                                    const f16* __restrict__ Kb,
                                                    const f16* __restrict__ Vtg,
                                                    f16* __restrict__ Ctx) {
  __shared__ f16 smem[8192];  // K img0 [0:4096) | img1 [4096:8192)
  const int t = threadIdx.x, lane = t & 63, w = t >> 6;
  const int fr = lane & 15, quad = lane >> 4;
  // XCD swizzle: 32 q-tiles of one (b,h) per XCD; 4 bh per XCD
  const int i = blockIdx.x;
  const int j = i >> 3;
  const int bh = ((i & 7) << 2) + (j >> 5);
  const int qt = j & 31;
  const int b = bh >> 4, h = bh & 15;

  const size_t qrow0 = (size_t)b * SEQ + qt * 64 + w * 16;

  // Q^T B-frags (one 16-q tile per wave), loop-invariant
  f16x8 Qf[2];
#pragma unroll
  for (int hf = 0; hf < 2; ++hf)
    Qf[hf] = *(const f16x8*)(Qb + (qrow0 + fr) * DM + h * HD + hf * 32 +
                             (quad << 3));

  // K reg-staging: lane -> (row16 = lane>>2, kc = lane&3), wave w rows 16w..+15
  const int krow = lane >> 2, kkc = lane & 3;
  const f16* Kg = Kb + ((size_t)b * SEQ + 16 * w + krow) * DM + h * HD + (kkc << 3);
  const int cwr = ((krow >> 1) << 3) | ((krow & 1) << 2) | (((krow >> 1) + kkc) & 3);
  const int wofs = (w << 9) + (cwr << 3);
  const int crd = ((fr >> 1) << 3) | ((fr & 1) << 2) | (((fr >> 1) + quad) & 3);

  // V frag-layout source (bh stride 131072, tile stride 4096)
  const f16* Vg = Vtg + ((size_t)bh << 17) + (quad << 8) + (fr << 2);

  f16x8 kreg[2];
  f16x4 va[4][4], vb[4][4];
  auto loadK = [&](int kt) {
#pragma unroll
    for (int hf = 0; hf < 2; ++hf)
      kreg[hf] = *(const f16x8*)(Kg + (size_t)kt * 64 * DM + hf * 32);
  };
  auto loadV = [&](int kt, f16x4 (&vr)[4][4]) {
#pragma unroll
    for (int kc = 0; kc < 4; ++kc)
#pragma unroll
      for (int dt = 0; dt < 4; ++dt)
        vr[dt][kc] = *(const f16x4*)(Vg + kt * 4096 + (kc << 10) + (dt << 6));
  };

  f32x4 acc[4] = {};
  float lacc = 0.f;

  f16* img0 = smem;
  f16* img1 = smem + 4096;

  loadK(0);
  loadV(0, va);
  *(f16x8*)(img0 + wofs) = kreg[0];
  *(f16x8*)(img0 + wofs + 2048) = kreg[1];

  auto body = [&](int kt, f16x4 (&vcur)[4][4], f16x4 (&vnxt)[4][4],
                  f16* imgR, f16* imgW) {
    __syncthreads();  // publishes imgR (tile kt); drains loads issued last body
    if (kt < 31) {
      loadK(kt + 1);
      loadV(kt + 1, vnxt);
    }
    f16x8 Kf[4][2];
#pragma unroll
    for (int mt = 0; mt < 4; ++mt)
#pragma unroll
      for (int hf = 0; hf < 2; ++hf)
        Kf[mt][hf] = *(const f16x8*)(imgR + (crd << 3) + hf * 2048 + (mt << 9));

    f32x4 z[4] = {};
#pragma unroll
    for (int mt = 0; mt < 4; ++mt) {
      z[mt] = __builtin_amdgcn_mfma_f32_16x16x32_f16(Kf[mt][0], Qf[0], z[mt],
                                                     0, 0, 0);
      z[mt] = __builtin_amdgcn_mfma_f32_16x16x32_f16(Kf[mt][1], Qf[1], z[mt],
                                                     0, 0, 0);
    }
    f16x4 pf[4];
#pragma unroll
    for (int mt = 0; mt < 4; ++mt) {
      const float p0 = __builtin_amdgcn_exp2f(z[mt][0]);
      const float p1 = __builtin_amdgcn_exp2f(z[mt][1]);
      const float p2 = __builtin_amdgcn_exp2f(z[mt][2]);
      const float p3 = __builtin_amdgcn_exp2f(z[mt][3]);
      lacc += (p0 + p1) + (p2 + p3);
      const f16x2 lo = __builtin_bit_cast(f16x2, __builtin_amdgcn_cvt_pkrtz(p0, p1));
      const f16x2 hi = __builtin_bit_cast(f16x2, __builtin_amdgcn_cvt_pkrtz(p2, p3));
      f16x4 pv; pv.x = lo.x; pv.y = lo.y; pv.z = hi.x; pv.w = hi.y;
      pf[mt] = pv;
    }

#pragma unroll
    for (int dt = 0; dt < 4; ++dt)
#pragma unroll
      for (int kc = 0; kc < 4; ++kc)
        acc[dt] = __builtin_amdgcn_mfma_f32_16x16x16f16(vcur[dt][kc], pf[kc],
                                                        acc[dt], 0, 0, 0);
    if (kt < 31) {
      *(f16x8*)(imgW + wofs) = kreg[0];
      *(f16x8*)(imgW + wofs + 2048) = kreg[1];
    }
  };

  for (int kt = 0; kt < 32; kt += 2) {
    body(kt, va, vb, img0, img1);
    body(kt + 1, vb, va, img1, img0);
  }

  // l reduction over quads (lanes fr, fr+16, fr+32, fr+48 share a q-col)
  float l = lacc;
  l += __shfl_xor(l, 16);
  l += __shfl_xor(l, 32);
  const float inv = __builtin_amdgcn_rcpf(l);

  __syncthreads();  // done with K images before epilogue reuse
  f16* T = smem + (w << 10);  // wave-private [16 q][64 d]
#pragma unroll
  for (int dt = 0; dt < 4; ++dt) {
    f16x4 o = {(f16)(acc[dt][0] * inv), (f16)(acc[dt][1] * inv),
               (f16)(acc[dt][2] * inv), (f16)(acc[dt][3] * inv)};
    *(f16x4*)(T + fr * 64 + dt * 16 + (quad << 2)) = o;
  }
#pragma unroll
  for (int p = 0; p < 2; ++p) {
    const int ql = p * 8 + (lane >> 3);
    const f16x8 v = *(const f16x8*)(T + ql * 64 + ((lane & 7) << 3));
    *(f16x8*)(Ctx + (qrow0 + ql) * DM + h * HD + ((lane & 7) << 3)) = v;
  }
}

extern "C" void kernel_launch(void* const* d_in, const int* in_sizes, int n_in,
                              void* d_out, int out_size, void* d_ws, size_t ws_size,
                              hipStream_t stream) {
  const float* x  = (const float*)d_in[0];
  const float* Wq = (const float*)d_in[1];
  const float* Wk = (const float*)d_in[2];
  const float* Wv = (const float*)d_in[3];
  const float* Wo = (const float*)d_in[4];

  char* ws = (char*)d_ws;
  f16* xb  = (f16*)(ws);                 // 8 MB; Wb contiguous after it
  f16* Wb  = (f16*)(ws + (8u << 20));    // 4 x 2 MB: Wq,Wk,Wv,Wo
  f16* Wqb = Wb;
  f16* Wkb = Wb + 1048576;
  f16* Wvb = Wb + 2097152;
  f16* Wob = Wb + 3145728;
  f16* Qb  = (f16*)(ws + (16u << 20));   // 8 MB (pre-scaled by log2e/32)
  f16* Kb  = (f16*)(ws + (24u << 20));
  f16* Vtg = (f16*)(ws + (32u << 20));   // frag-layout V, 8 MB
  f16* Ctx = (f16*)(ws + (40u << 20));   // -> 48 MB total

  cast_all<<<8192, 256, 0, stream>>>(x, Wq, Wk, Wv, Wo, xb);

  gemm_qkv<<<dim3(24, 32), 256, 0, stream>>>(xb, Wqb, Wkb, Wvb, Qb, Kb, Vtg);
  attn_mfma<<<dim3(2 * NH * (SEQ / 64)), 256, 0, stream>>>(Qb, Kb, Vtg, Ctx);
  gemm_out<<<dim3(16, 32), 256, 0, stream>>>(Ctx, Wob, (float*)d_out);
}

// Round 12
// 216.687 us; speedup vs baseline: 1.3328x; 1.3328x over previous
//
#include <hip/hip_runtime.h>
#include <cstddef>
#include <cstdint>

#define SEQ 2048
#define DM 1024
#define NH 16
#define HD 64

typedef _Float16 f16;
typedef __attribute__((ext_vector_type(8))) _Float16 f16x8;
typedef __attribute__((ext_vector_type(4))) _Float16 f16x4;
typedef __attribute__((ext_vector_type(2))) _Float16 f16x2;
typedef __attribute__((ext_vector_type(4))) float f32x4;

// one launch: cast x (1M float4) + 4 weights (256K float4 each) into the
// contiguous 16 MB f16 region [xb | Wq | Wk | Wv | Wo]
__global__ __launch_bounds__(256) void cast_all(const float* __restrict__ x,
                                                const float* __restrict__ Wq,
                                                const float* __restrict__ Wk,
                                                const float* __restrict__ Wv,
                                                const float* __restrict__ Wo,
                                                f16* __restrict__ dst) {
  const int i = blockIdx.x * 256 + threadIdx.x;  // float4 index, 2M total
  const float* src;
  int off;
  if (i < 1048576) {
    src = x; off = i;
  } else {
    const int j = i - 1048576;
    const int wsel = j >> 18;
    src = (wsel == 0) ? Wq : (wsel == 1) ? Wk : (wsel == 2) ? Wv : Wo;
    off = j & 262143;
  }
  const float4 v = ((const float4*)src)[off];
  f16x4 o = {(f16)v.x, (f16)v.y, (f16)v.z, (f16)v.w};
  ((f16x4*)dst)[i] = o;
}

__device__ __forceinline__ void gload16(const void* g, void* lds) {
  __builtin_amdgcn_global_load_lds((const __attribute__((address_space(1))) void*)g,
                                   (__attribute__((address_space(3))) void*)lds,
                                   16, 0, 0);
}

// ---------------------------------------------------------------------------
// f16 GEMM mainloop (m97 structure), 128x128 tile.
// ---------------------------------------------------------------------------
__device__ __forceinline__ void gemm_tile(const f16* __restrict__ A,
                                          const f16* __restrict__ B,
                                          f16* As, f16* Bs,
                                          int K, f32x4 acc[4][4]) {
  const int t = threadIdx.x;
  const int lane = t & 63;
  const int w = t >> 6;
  const int wm = (w & 1) << 6, wn = (w >> 1) << 6;
  const int srow = lane >> 2, scol = lane & 3;
  const int fr = lane & 15, q = lane >> 4;
  for (int k0 = 0; k0 < K; k0 += 32) {
    __syncthreads();
#pragma unroll
    for (int c = 0; c < 2; ++c) {
      const int chunk = (w << 1) + c;
      const int row = (chunk << 4) + srow;
      gload16(A + (size_t)row * K + k0 + (scol << 3), As + (chunk << 9));
      gload16(B + (size_t)row * K + k0 + (scol << 3), Bs + (chunk << 9));
    }
    __syncthreads();
    f16x8 af[4], bfr[4];
#pragma unroll
    for (int i = 0; i < 4; ++i)
      af[i] = *(const f16x8*)(As + (wm + (i << 4) + fr) * 32 + (q << 3));
#pragma unroll
    for (int j = 0; j < 4; ++j)
      bfr[j] = *(const f16x8*)(Bs + (wn + (j << 4) + fr) * 32 + (q << 3));
#pragma unroll
    for (int i = 0; i < 4; ++i)
#pragma unroll
      for (int j = 0; j < 4; ++j)
        acc[i][j] = __builtin_amdgcn_mfma_f32_16x16x32_f16(af[i], bfr[j],
                                                           acc[i][j], 0, 0, 0);
  }
}

// Fused QKV projection. Q pre-scaled by log2(e)/sqrt(d_model).
// Q/K epilogue via LDS transpose -> coalesced f16x8 stores; V epilogue:
// direct frag-layout f16x4 stores.
//   Vtg flat(d,s) = bh*131072 + (s>>6)*4096 + ((s>>2)&15)*256 + d*4 + (s&3)
#define QSCALE 0.04508422003f /* 1.4426950409/32 */
__global__ __launch_bounds__(256) void gemm_qkv(
    const f16* __restrict__ xb, const f16* __restrict__ Wqb,
    const f16* __restrict__ Wkb, const f16* __restrict__ Wvb,
    f16* __restrict__ Qb, f16* __restrict__ Kb, f16* __restrict__ Vtg) {
  __shared__ f16 smem[16896];
  f16* As = smem;
  f16* Bs = smem + 4096;
  const int which = blockIdx.x >> 3;
  const int bn = (blockIdx.x & 7) << 7;
  const int bm = blockIdx.y << 7;
  const f16* B = (which == 0) ? Wqb : (which == 1) ? Wkb : Wvb;
  f32x4 acc[4][4] = {};
  gemm_tile(xb + (size_t)bm * DM, B + (size_t)bn * DM, As, Bs, DM, acc);
  const int t = threadIdx.x;
  const int lane = t & 63, w = t >> 6;
  const int wm = (w & 1) << 6, wn = (w >> 1) << 6;
  const int col = lane & 15, q = lane >> 4;
  if (which < 2) {
    f16* C = (which == 0) ? Qb : Kb;
    const float sc = (which == 0) ? QSCALE : 1.0f;
    __syncthreads();
#pragma unroll
    for (int i = 0; i < 4; ++i) {
      const int m0 = wm + (i << 4) + (q << 2);
#pragma unroll
      for (int j = 0; j < 4; ++j) {
        const int n = wn + (j << 4) + col;
#pragma unroll
        for (int r = 0; r < 4; ++r)
          smem[(m0 + r) * 132 + n] = (f16)(acc[i][j][r] * sc);
      }
    }
    __syncthreads();
#pragma unroll
    for (int p = 0; p < 8; ++p) {
      const int idx = t + (p << 8);
      const int row = idx >> 4, c8 = (idx & 15) << 3;
      const f16x8 v = *(const f16x8*)(smem + row * 132 + c8);
      *(f16x8*)(C + (size_t)(bm + row) * DM + bn + c8) = v;
    }
  } else {
    const int b = bm >> 11, sb = bm & 2047;
#pragma unroll
    for (int i = 0; i < 4; ++i) {
      const int sg = sb + wm + (i << 4) + (q << 2);
#pragma unroll
      for (int j = 0; j < 4; ++j) {
        const int n = bn + wn + (j << 4) + col;
        const int bh = (b << 4) + (n >> 6), d = n & 63;
        f16x4 o = {(f16)acc[i][j][0], (f16)acc[i][j][1],
                   (f16)acc[i][j][2], (f16)acc[i][j][3]};
        const size_t flat = ((size_t)bh << 17) + ((size_t)(sg >> 6) << 12) +
                            (((sg >> 2) & 15) << 8) + (d << 2);
        *(f16x4*)(Vtg + flat) = o;
      }
    }
  }
}

// 128(M)x64(N) tile -> grid 512 = 2 blocks/CU.
__global__ __launch_bounds__(256) void gemm_out(const f16* __restrict__ Ab,
                                                const f16* __restrict__ Wob,
                                                float* __restrict__ out) {
  __shared__ f16 As[4096];  // 128 x 32
  __shared__ f16 Bs[2048];  // 64 x 32
  const int bn = blockIdx.x << 6, bm = blockIdx.y << 7;
  const int t = threadIdx.x, lane = t & 63, w = t >> 6;
  const int wm = (w & 1) << 6, wn = (w >> 1) << 5;
  const int srow = lane >> 2, scol = lane & 3;
  const int fr = lane & 15, q = lane >> 4;
  f32x4 acc[4][2] = {};
  for (int k0 = 0; k0 < DM; k0 += 32) {
    __syncthreads();
#pragma unroll
    for (int c = 0; c < 2; ++c) {
      const int chunk = (w << 1) + c;
      const int row = (chunk << 4) + srow;
      gload16(Ab + (size_t)(bm + row) * DM + k0 + (scol << 3), As + (chunk << 9));
    }
    {
      const int row = (w << 4) + srow;
      gload16(Wob + (size_t)(bn + row) * DM + k0 + (scol << 3), Bs + (w << 9));
    }
    __syncthreads();
    f16x8 af[4], bfr[2];
#pragma unroll
    for (int i = 0; i < 4; ++i)
      af[i] = *(const f16x8*)(As + (wm + (i << 4) + fr) * 32 + (q << 3));
#pragma unroll
    for (int j = 0; j < 2; ++j)
      bfr[j] = *(const f16x8*)(Bs + (wn + (j << 4) + fr) * 32 + (q << 3));
#pragma unroll
    for (int i = 0; i < 4; ++i)
#pragma unroll
      for (int j = 0; j < 2; ++j)
        acc[i][j] = __builtin_amdgcn_mfma_f32_16x16x32_f16(af[i], bfr[j],
                                                           acc[i][j], 0, 0, 0);
  }
  const int col = lane & 15;
#pragma unroll
  for (int i = 0; i < 4; ++i) {
    const int m = bm + wm + (i << 4) + (q << 2);
#pragma unroll
    for (int j = 0; j < 2; ++j) {
      const int n = bn + wn + (j << 4) + col;
#pragma unroll
      for (int r = 0; r < 4; ++r)
        out[(size_t)(m + r) * DM + n] = acc[i][j][r];
    }
  }
}

// ---------------------------------------------------------------------------
// MFMA flash attention R12: q-tile 64 (grid 1024 -> 4 blocks/CU available) with
// NO launch-bounds VGPR cap (R11's (256,4) forced 64 VGPRs -> 200 MB scratch
// spills). Natural VGPR ~100 gives 4-5 waves/EU; occupancy doubles vs R9.
// ---------------------------------------------------------------------------
__global__ __launch_bounds__(256) void attn_mfma(const f16* __restrict__ Qb,
                                                 const f16* __restrict__ Kb,
                                                 const f16* __restrict__ Vtg,
                                                 f16* __restrict__ Ctx) {
  __shared__ f16 smem[8192];  // K img0 [0:4096) | img1 [4096:8192)
  const int t = threadIdx.x, lane = t & 63, w = t >> 6;
  const int fr = lane & 15, quad = lane >> 4;
  // XCD swizzle: 32 q-tiles of one (b,h) per XCD; 4 bh per XCD
  const int i = blockIdx.x;
  const int j = i >> 3;
  const int bh = ((i & 7) << 2) + (j >> 5);
  const int qt = j & 31;
  const int b = bh >> 4, h = bh & 15;

  const size_t qrow0 = (size_t)b * SEQ + qt * 64 + w * 16;

  // Q^T B-frags (one 16-q tile per wave), loop-invariant
  f16x8 Qf[2];
#pragma unroll
  for (int hf = 0; hf < 2; ++hf)
    Qf[hf] = *(const f16x8*)(Qb + (qrow0 + fr) * DM + h * HD + hf * 32 +
                             (quad << 3));

  // K reg-staging: lane -> (row16 = lane>>2, kc = lane&3), wave w rows 16w..+15
  const int krow = lane >> 2, kkc = lane & 3;
  const f16* Kg = Kb + ((size_t)b * SEQ + 16 * w + krow) * DM + h * HD + (kkc << 3);
  const int cwr = ((krow >> 1) << 3) | ((krow & 1) << 2) | (((krow >> 1) + kkc) & 3);
  const int wofs = (w << 9) + (cwr << 3);
  const int crd = ((fr >> 1) << 3) | ((fr & 1) << 2) | (((fr >> 1) + quad) & 3);

  // V frag-layout source (bh stride 131072, tile stride 4096)
  const f16* Vg = Vtg + ((size_t)bh << 17) + (quad << 8) + (fr << 2);

  f16x8 kreg[2];
  f16x4 va[4][4], vb[4][4];
  auto loadK = [&](int kt) {
#pragma unroll
    for (int hf = 0; hf < 2; ++hf)
      kreg[hf] = *(const f16x8*)(Kg + (size_t)kt * 64 * DM + hf * 32);
  };
  auto loadV = [&](int kt, f16x4 (&vr)[4][4]) {
#pragma unroll
    for (int kc = 0; kc < 4; ++kc)
#pragma unroll
      for (int dt = 0; dt < 4; ++dt)
        vr[dt][kc] = *(const f16x4*)(Vg + kt * 4096 + (kc << 10) + (dt << 6));
  };

  f32x4 acc[4] = {};
  float lacc = 0.f;

  f16* img0 = smem;
  f16* img1 = smem + 4096;

  loadK(0);
  loadV(0, va);
  *(f16x8*)(img0 + wofs) = kreg[0];
  *(f16x8*)(img0 + wofs + 2048) = kreg[1];

  auto body = [&](int kt, f16x4 (&vcur)[4][4], f16x4 (&vnxt)[4][4],
                  f16* imgR, f16* imgW) {
    __syncthreads();  // publishes imgR (tile kt); drains loads issued last body
    if (kt < 31) {
      loadK(kt + 1);
      loadV(kt + 1, vnxt);
    }
    f16x8 Kf[4][2];
#pragma unroll
    for (int mt = 0; mt < 4; ++mt)
#pragma unroll
      for (int hf = 0; hf < 2; ++hf)
        Kf[mt][hf] = *(const f16x8*)(imgR + (crd << 3) + hf * 2048 + (mt << 9));

    f32x4 z[4] = {};
#pragma unroll
    for (int mt = 0; mt < 4; ++mt) {
      z[mt] = __builtin_amdgcn_mfma_f32_16x16x32_f16(Kf[mt][0], Qf[0], z[mt],
                                                     0, 0, 0);
      z[mt] = __builtin_amdgcn_mfma_f32_16x16x32_f16(Kf[mt][1], Qf[1], z[mt],
                                                     0, 0, 0);
    }
    f16x4 pf[4];
#pragma unroll
    for (int mt = 0; mt < 4; ++mt) {
      const float p0 = __builtin_amdgcn_exp2f(z[mt][0]);
      const float p1 = __builtin_amdgcn_exp2f(z[mt][1]);
      const float p2 = __builtin_amdgcn_exp2f(z[mt][2]);
      const float p3 = __builtin_amdgcn_exp2f(z[mt][3]);
      lacc += (p0 + p1) + (p2 + p3);
      const f16x2 lo = __builtin_bit_cast(f16x2, __builtin_amdgcn_cvt_pkrtz(p0, p1));
      const f16x2 hi = __builtin_bit_cast(f16x2, __builtin_amdgcn_cvt_pkrtz(p2, p3));
      f16x4 pv; pv.x = lo.x; pv.y = lo.y; pv.z = hi.x; pv.w = hi.y;
      pf[mt] = pv;
    }

#pragma unroll
    for (int dt = 0; dt < 4; ++dt)
#pragma unroll
      for (int kc = 0; kc < 4; ++kc)
        acc[dt] = __builtin_amdgcn_mfma_f32_16x16x16f16(vcur[dt][kc], pf[kc],
                                                        acc[dt], 0, 0, 0);
    if (kt < 31) {
      *(f16x8*)(imgW + wofs) = kreg[0];
      *(f16x8*)(imgW + wofs + 2048) = kreg[1];
    }
  };

  for (int kt = 0; kt < 32; kt += 2) {
    body(kt, va, vb, img0, img1);
    body(kt + 1, vb, va, img1, img0);
  }

  // l reduction over quads (lanes fr, fr+16, fr+32, fr+48 share a q-col)
  float l = lacc;
  l += __shfl_xor(l, 16);
  l += __shfl_xor(l, 32);
  const float inv = __builtin_amdgcn_rcpf(l);

  __syncthreads();  // done with K images before epilogue reuse
  f16* T = smem + (w << 10);  // wave-private [16 q][64 d]
#pragma unroll
  for (int dt = 0; dt < 4; ++dt) {
    f16x4 o = {(f16)(acc[dt][0] * inv), (f16)(acc[dt][1] * inv),
               (f16)(acc[dt][2] * inv), (f16)(acc[dt][3] * inv)};
    *(f16x4*)(T + fr * 64 + dt * 16 + (quad << 2)) = o;
  }
#pragma unroll
  for (int p = 0; p < 2; ++p) {
    const int ql = p * 8 + (lane >> 3);
    const f16x8 v = *(const f16x8*)(T + ql * 64 + ((lane & 7) << 3));
    *(f16x8*)(Ctx + (qrow0 + ql) * DM + h * HD + ((lane & 7) << 3)) = v;
  }
}

extern "C" void kernel_launch(void* const* d_in, const int* in_sizes, int n_in,
                              void* d_out, int out_size, void* d_ws, size_t ws_size,
                              hipStream_t stream) {
  const float* x  = (const float*)d_in[0];
  const float* Wq = (const float*)d_in[1];
  const float* Wk = (const float*)d_in[2];
  const float* Wv = (const float*)d_in[3];
  const float* Wo = (const float*)d_in[4];

  char* ws = (char*)d_ws;
  f16* xb  = (f16*)(ws);                 // 8 MB; Wb contiguous after it
  f16* Wb  = (f16*)(ws + (8u << 20));    // 4 x 2 MB: Wq,Wk,Wv,Wo
  f16* Wqb = Wb;
  f16* Wkb = Wb + 1048576;
  f16* Wvb = Wb + 2097152;
  f16* Wob = Wb + 3145728;
  f16* Qb  = (f16*)(ws + (16u << 20));   // 8 MB (pre-scaled by log2e/32)
  f16* Kb  = (f16*)(ws + (24u << 20));
  f16* Vtg = (f16*)(ws + (32u << 20));   // frag-layout V, 8 MB
  f16* Ctx = (f16*)(ws + (40u << 20));   // -> 48 MB total

  cast_all<<<8192, 256, 0, stream>>>(x, Wq, Wk, Wv, Wo, xb);

  gemm_qkv<<<dim3(24, 32), 256, 0, stream>>>(xb, Wqb, Wkb, Wvb, Qb, Kb, Vtg);
  attn_mfma<<<dim3(2 * NH * (SEQ / 64)), 256, 0, stream>>>(Qb, Kb, Vtg, Ctx);
  gemm_out<<<dim3(16, 32), 256, 0, stream>>>(Ctx, Wob, (float*)d_out);
}

// Round 13
// 197.736 us; speedup vs baseline: 1.4605x; 1.0958x over previous
//
#include <hip/hip_runtime.h>
#include <cstddef>
#include <cstdint>

#define SEQ 2048
#define DM 1024
#define NH 16
#define HD 64

typedef _Float16 f16;
typedef __attribute__((ext_vector_type(8))) _Float16 f16x8;
typedef __attribute__((ext_vector_type(4))) _Float16 f16x4;
typedef __attribute__((ext_vector_type(2))) _Float16 f16x2;
typedef __attribute__((ext_vector_type(4))) float f32x4;

// one launch: cast x (1M float4) + 4 weights (256K float4 each) into the
// contiguous 16 MB f16 region [xb | Wq | Wk | Wv | Wo]
__global__ __launch_bounds__(256) void cast_all(const float* __restrict__ x,
                                                const float* __restrict__ Wq,
                                                const float* __restrict__ Wk,
                                                const float* __restrict__ Wv,
                                                const float* __restrict__ Wo,
                                                f16* __restrict__ dst) {
  const int i = blockIdx.x * 256 + threadIdx.x;  // float4 index, 2M total
  const float* src;
  int off;
  if (i < 1048576) {
    src = x; off = i;
  } else {
    const int j = i - 1048576;
    const int wsel = j >> 18;
    src = (wsel == 0) ? Wq : (wsel == 1) ? Wk : (wsel == 2) ? Wv : Wo;
    off = j & 262143;
  }
  const float4 v = ((const float4*)src)[off];
  f16x4 o = {(f16)v.x, (f16)v.y, (f16)v.z, (f16)v.w};
  ((f16x4*)dst)[i] = o;
}

__device__ __forceinline__ void gload16(const void* g, void* lds) {
  __builtin_amdgcn_global_load_lds((const __attribute__((address_space(1))) void*)g,
                                   (__attribute__((address_space(3))) void*)lds,
                                   16, 0, 0);
}

// ---------------------------------------------------------------------------
// f16 GEMM mainloop (m97 structure), 128x128 tile.
// ---------------------------------------------------------------------------
__device__ __forceinline__ void gemm_tile(const f16* __restrict__ A,
                                          const f16* __restrict__ B,
                                          f16* As, f16* Bs,
                                          int K, f32x4 acc[4][4]) {
  const int t = threadIdx.x;
  const int lane = t & 63;
  const int w = t >> 6;
  const int wm = (w & 1) << 6, wn = (w >> 1) << 6;
  const int srow = lane >> 2, scol = lane & 3;
  const int fr = lane & 15, q = lane >> 4;
  for (int k0 = 0; k0 < K; k0 += 32) {
    __syncthreads();
#pragma unroll
    for (int c = 0; c < 2; ++c) {
      const int chunk = (w << 1) + c;
      const int row = (chunk << 4) + srow;
      gload16(A + (size_t)row * K + k0 + (scol << 3), As + (chunk << 9));
      gload16(B + (size_t)row * K + k0 + (scol << 3), Bs + (chunk << 9));
    }
    __syncthreads();
    f16x8 af[4], bfr[4];
#pragma unroll
    for (int i = 0; i < 4; ++i)
      af[i] = *(const f16x8*)(As + (wm + (i << 4) + fr) * 32 + (q << 3));
#pragma unroll
    for (int j = 0; j < 4; ++j)
      bfr[j] = *(const f16x8*)(Bs + (wn + (j << 4) + fr) * 32 + (q << 3));
#pragma unroll
    for (int i = 0; i < 4; ++i)
#pragma unroll
      for (int j = 0; j < 4; ++j)
        acc[i][j] = __builtin_amdgcn_mfma_f32_16x16x32_f16(af[i], bfr[j],
                                                           acc[i][j], 0, 0, 0);
  }
}

// Fused QKV projection. Q pre-scaled by log2(e)/sqrt(d_model).
//   Vtg flat(d,s) = bh*131072 + (s>>6)*4096 + ((s>>2)&15)*256 + d*4 + (s&3)
#define QSCALE 0.04508422003f /* 1.4426950409/32 */
__global__ __launch_bounds__(256) void gemm_qkv(
    const f16* __restrict__ xb, const f16* __restrict__ Wqb,
    const f16* __restrict__ Wkb, const f16* __restrict__ Wvb,
    f16* __restrict__ Qb, f16* __restrict__ Kb, f16* __restrict__ Vtg) {
  __shared__ f16 smem[16896];
  f16* As = smem;
  f16* Bs = smem + 4096;
  const int which = blockIdx.x >> 3;
  const int bn = (blockIdx.x & 7) << 7;
  const int bm = blockIdx.y << 7;
  const f16* B = (which == 0) ? Wqb : (which == 1) ? Wkb : Wvb;
  f32x4 acc[4][4] = {};
  gemm_tile(xb + (size_t)bm * DM, B + (size_t)bn * DM, As, Bs, DM, acc);
  const int t = threadIdx.x;
  const int lane = t & 63, w = t >> 6;
  const int wm = (w & 1) << 6, wn = (w >> 1) << 6;
  const int col = lane & 15, q = lane >> 4;
  if (which < 2) {
    f16* C = (which == 0) ? Qb : Kb;
    const float sc = (which == 0) ? QSCALE : 1.0f;
    __syncthreads();
#pragma unroll
    for (int i = 0; i < 4; ++i) {
      const int m0 = wm + (i << 4) + (q << 2);
#pragma unroll
      for (int j = 0; j < 4; ++j) {
        const int n = wn + (j << 4) + col;
#pragma unroll
        for (int r = 0; r < 4; ++r)
          smem[(m0 + r) * 132 + n] = (f16)(acc[i][j][r] * sc);
      }
    }
    __syncthreads();
#pragma unroll
    for (int p = 0; p < 8; ++p) {
      const int idx = t + (p << 8);
      const int row = idx >> 4, c8 = (idx & 15) << 3;
      const f16x8 v = *(const f16x8*)(smem + row * 132 + c8);
      *(f16x8*)(C + (size_t)(bm + row) * DM + bn + c8) = v;
    }
  } else {
    const int b = bm >> 11, sb = bm & 2047;
#pragma unroll
    for (int i = 0; i < 4; ++i) {
      const int sg = sb + wm + (i << 4) + (q << 2);
#pragma unroll
      for (int j = 0; j < 4; ++j) {
        const int n = bn + wn + (j << 4) + col;
        const int bh = (b << 4) + (n >> 6), d = n & 63;
        f16x4 o = {(f16)acc[i][j][0], (f16)acc[i][j][1],
                   (f16)acc[i][j][2], (f16)acc[i][j][3]};
        const size_t flat = ((size_t)bh << 17) + ((size_t)(sg >> 6) << 12) +
                            (((sg >> 2) & 15) << 8) + (d << 2);
        *(f16x4*)(Vtg + flat) = o;
      }
    }
  }
}

// 128(M)x64(N) tile -> grid 512 = 2 blocks/CU.
__global__ __launch_bounds__(256) void gemm_out(const f16* __restrict__ Ab,
                                                const f16* __restrict__ Wob,
                                                float* __restrict__ out) {
  __shared__ f16 As[4096];  // 128 x 32
  __shared__ f16 Bs[2048];  // 64 x 32
  const int bn = blockIdx.x << 6, bm = blockIdx.y << 7;
  const int t = threadIdx.x, lane = t & 63, w = t >> 6;
  const int wm = (w & 1) << 6, wn = (w >> 1) << 5;
  const int srow = lane >> 2, scol = lane & 3;
  const int fr = lane & 15, q = lane >> 4;
  f32x4 acc[4][2] = {};
  for (int k0 = 0; k0 < DM; k0 += 32) {
    __syncthreads();
#pragma unroll
    for (int c = 0; c < 2; ++c) {
      const int chunk = (w << 1) + c;
      const int row = (chunk << 4) + srow;
      gload16(Ab + (size_t)(bm + row) * DM + k0 + (scol << 3), As + (chunk << 9));
    }
    {
      const int row = (w << 4) + srow;
      gload16(Wob + (size_t)(bn + row) * DM + k0 + (scol << 3), Bs + (w << 9));
    }
    __syncthreads();
    f16x8 af[4], bfr[2];
#pragma unroll
    for (int i = 0; i < 4; ++i)
      af[i] = *(const f16x8*)(As + (wm + (i << 4) + fr) * 32 + (q << 3));
#pragma unroll
    for (int j = 0; j < 2; ++j)
      bfr[j] = *(const f16x8*)(Bs + (wn + (j << 4) + fr) * 32 + (q << 3));
#pragma unroll
    for (int i = 0; i < 4; ++i)
#pragma unroll
      for (int j = 0; j < 2; ++j)
        acc[i][j] = __builtin_amdgcn_mfma_f32_16x16x32_f16(af[i], bfr[j],
                                                           acc[i][j], 0, 0, 0);
  }
  const int col = lane & 15;
#pragma unroll
  for (int i = 0; i < 4; ++i) {
    const int m = bm + wm + (i << 4) + (q << 2);
#pragma unroll
    for (int j = 0; j < 2; ++j) {
      const int n = bn + wn + (j << 4) + col;
#pragma unroll
      for (int r = 0; r < 4; ++r)
        out[(size_t)(m + r) * DM + n] = acc[i][j][r];
    }
  }
}

// ---------------------------------------------------------------------------
// MFMA flash attention R13: R9's q128 body (the efficient iteration shape),
// split-K over 2 halves of the k-range -> grid 1024 = 4 blocks/CU.
// Each block writes split-normalized partials: Po (f16, [bh][qt][q][d]) and
// Pl (f32 row sums). attn_combine merges: (l0*o0 + l1*o1)/(l0+l1).
// ---------------------------------------------------------------------------
__global__ __launch_bounds__(256) void attn_mfma(const f16* __restrict__ Qb,
                                                 const f16* __restrict__ Kb,
                                                 const f16* __restrict__ Vtg,
                                                 f16* __restrict__ Po0,
                                                 f16* __restrict__ Po1,
                                                 float* __restrict__ Pl0,
                                                 float* __restrict__ Pl1) {
  __shared__ f16 smem[8192];  // K img0 [0:4096) | img1 [4096:8192)
  const int t = threadIdx.x, lane = t & 63, w = t >> 6;
  const int fr = lane & 15, quad = lane >> 4;
  // XCD swizzle: 4 bh per XCD; per bh: 16 q-tiles x 2 splits
  const int i = blockIdx.x;
  const int j = i >> 3;                    // 0..127
  const int bh = ((i & 7) << 2) + (j >> 5);
  const int rem = j & 31;
  const int sp = rem >> 4;                 // k-split 0/1
  const int qt16 = rem & 15;
  const int b = bh >> 4, h = bh & 15;
  const int kbeg = sp << 4;                // 16 k-tiles per split

  const size_t qrow0 = (size_t)b * SEQ + qt16 * 128 + w * 32;

  // Q^T B-frags, loop-invariant
  f16x8 Qf[2][2];
#pragma unroll
  for (int qt = 0; qt < 2; ++qt)
#pragma unroll
    for (int hf = 0; hf < 2; ++hf)
      Qf[qt][hf] = *(const f16x8*)(Qb + (qrow0 + qt * 16 + fr) * DM + h * HD +
                                   hf * 32 + (quad << 3));

  // K reg-staging: lane -> (row16 = lane>>2, kc = lane&3), wave w rows 16w..+15
  const int krow = lane >> 2, kkc = lane & 3;
  const f16* Kg = Kb + ((size_t)b * SEQ + 16 * w + krow) * DM + h * HD + (kkc << 3);
  const int cwr = ((krow >> 1) << 3) | ((krow & 1) << 2) | (((krow >> 1) + kkc) & 3);
  const int wofs = (w << 9) + (cwr << 3);
  const int crd = ((fr >> 1) << 3) | ((fr & 1) << 2) | (((fr >> 1) + quad) & 3);

  // V frag-layout source (bh stride 131072, tile stride 4096)
  const f16* Vg = Vtg + ((size_t)bh << 17) + (quad << 8) + (fr << 2);

  f16x8 kreg[2];
  f16x4 va[4][4], vb[4][4];
  auto loadK = [&](int kt) {
#pragma unroll
    for (int hf = 0; hf < 2; ++hf)
      kreg[hf] = *(const f16x8*)(Kg + (size_t)kt * 64 * DM + hf * 32);
  };
  auto loadV = [&](int kt, f16x4 (&vr)[4][4]) {
#pragma unroll
    for (int kc = 0; kc < 4; ++kc)
#pragma unroll
      for (int dt = 0; dt < 4; ++dt)
        vr[dt][kc] = *(const f16x4*)(Vg + kt * 4096 + (kc << 10) + (dt << 6));
  };

  f32x4 acc[2][4] = {};
  float lacc[2] = {0.f, 0.f};

  f16* img0 = smem;
  f16* img1 = smem + 4096;

  loadK(kbeg);
  loadV(kbeg, va);
  *(f16x8*)(img0 + wofs) = kreg[0];
  *(f16x8*)(img0 + wofs + 2048) = kreg[1];

  auto body = [&](int n, f16x4 (&vcur)[4][4], f16x4 (&vnxt)[4][4],
                  f16* imgR, f16* imgW) {
    __syncthreads();  // publishes imgR; drains loads issued last body
    if (n < 15) {
      loadK(kbeg + n + 1);
      loadV(kbeg + n + 1, vnxt);
    }
    f16x8 Kf[4][2];
#pragma unroll
    for (int mt = 0; mt < 4; ++mt)
#pragma unroll
      for (int hf = 0; hf < 2; ++hf)
        Kf[mt][hf] = *(const f16x8*)(imgR + (crd << 3) + hf * 2048 + (mt << 9));

    f16x4 pf[2][4];
#pragma unroll
    for (int qt = 0; qt < 2; ++qt) {
      f32x4 z[4] = {};
#pragma unroll
      for (int mt = 0; mt < 4; ++mt) {
        z[mt] = __builtin_amdgcn_mfma_f32_16x16x32_f16(Kf[mt][0], Qf[qt][0],
                                                       z[mt], 0, 0, 0);
        z[mt] = __builtin_amdgcn_mfma_f32_16x16x32_f16(Kf[mt][1], Qf[qt][1],
                                                       z[mt], 0, 0, 0);
      }
#pragma unroll
      for (int mt = 0; mt < 4; ++mt) {
        const float p0 = __builtin_amdgcn_exp2f(z[mt][0]);
        const float p1 = __builtin_amdgcn_exp2f(z[mt][1]);
        const float p2 = __builtin_amdgcn_exp2f(z[mt][2]);
        const float p3 = __builtin_amdgcn_exp2f(z[mt][3]);
        lacc[qt] += (p0 + p1) + (p2 + p3);
        const f16x2 lo = __builtin_bit_cast(f16x2, __builtin_amdgcn_cvt_pkrtz(p0, p1));
        const f16x2 hi = __builtin_bit_cast(f16x2, __builtin_amdgcn_cvt_pkrtz(p2, p3));
        f16x4 pv; pv.x = lo.x; pv.y = lo.y; pv.z = hi.x; pv.w = hi.y;
        pf[qt][mt] = pv;
      }
    }

#pragma unroll
    for (int dt = 0; dt < 4; ++dt)
#pragma unroll
      for (int kc = 0; kc < 4; ++kc)
#pragma unroll
        for (int qt = 0; qt < 2; ++qt)
          acc[qt][dt] = __builtin_amdgcn_mfma_f32_16x16x16f16(vcur[dt][kc],
                                                              pf[qt][kc],
                                                              acc[qt][dt], 0, 0, 0);
    if (n < 15) {
      *(f16x8*)(imgW + wofs) = kreg[0];
      *(f16x8*)(imgW + wofs + 2048) = kreg[1];
    }
  };

  for (int n = 0; n < 16; n += 2) {
    body(n, va, vb, img0, img1);
    body(n + 1, vb, va, img1, img0);
  }

  // l reduction over quads (lanes fr, fr+16, fr+32, fr+48 share a q-col)
  float lsum[2], inv[2];
#pragma unroll
  for (int qt = 0; qt < 2; ++qt) {
    float l = lacc[qt];
    l += __shfl_xor(l, 16);
    l += __shfl_xor(l, 32);
    lsum[qt] = l;
    inv[qt] = __builtin_amdgcn_rcpf(l);
  }

  f16* Po = sp ? Po1 : Po0;
  float* Pl = sp ? Pl1 : Pl0;
  const size_t pbase = ((size_t)(bh * 16 + qt16) * 128);

  if (quad == 0) {
#pragma unroll
    for (int qt = 0; qt < 2; ++qt)
      Pl[pbase + w * 32 + qt * 16 + fr] = lsum[qt];
  }

  __syncthreads();  // done with K images before epilogue reuse
  f16* T = smem + (w << 11);  // wave-private [32 q][64 d]
#pragma unroll
  for (int qt = 0; qt < 2; ++qt)
#pragma unroll
    for (int dt = 0; dt < 4; ++dt) {
      f16x4 o = {(f16)(acc[qt][dt][0] * inv[qt]), (f16)(acc[qt][dt][1] * inv[qt]),
                 (f16)(acc[qt][dt][2] * inv[qt]), (f16)(acc[qt][dt][3] * inv[qt])};
      *(f16x4*)(T + (qt * 16 + fr) * 64 + dt * 16 + (quad << 2)) = o;
    }
#pragma unroll
  for (int p = 0; p < 4; ++p) {
    const int ql = p * 8 + (lane >> 3);
    const f16x8 v = *(const f16x8*)(T + ql * 64 + ((lane & 7) << 3));
    *(f16x8*)(Po + (pbase + w * 32 + ql) * 64 + ((lane & 7) << 3)) = v;
  }
}

// Merge the two k-splits: Ctx = (l0*o0 + l1*o1)/(l0+l1), coalesced f16x8.
__global__ __launch_bounds__(256) void attn_combine(
    const f16* __restrict__ Po0, const f16* __restrict__ Po1,
    const float* __restrict__ Pl0, const float* __restrict__ Pl1,
    f16* __restrict__ Ctx) {
  const int idx = blockIdx.x * 256 + threadIdx.x;  // 0..524287
  const int m = idx >> 7, g = idx & 127;
  const int b = m >> 11, s = m & 2047;
  const int h = g >> 3;
  const int bh = (b << 4) + h;
  const int qt = s >> 7, q = s & 127;
  const size_t po = ((size_t)(bh * 16 + qt) * 128 + q) * 64 + ((g & 7) << 3);
  const int pl = (bh * 16 + qt) * 128 + q;
  const f16x8 o0 = *(const f16x8*)(Po0 + po);
  const f16x8 o1 = *(const f16x8*)(Po1 + po);
  const float l0 = Pl0[pl], l1 = Pl1[pl];
  const float inv = __builtin_amdgcn_rcpf(l0 + l1);
  const float w0 = l0 * inv, w1 = l1 * inv;
  f16x8 r;
#pragma unroll
  for (int j = 0; j < 8; ++j)
    r[j] = (f16)(w0 * (float)o0[j] + w1 * (float)o1[j]);
  *(f16x8*)(Ctx + (size_t)m * DM + (size_t)g * 8) = r;
}

extern "C" void kernel_launch(void* const* d_in, const int* in_sizes, int n_in,
                              void* d_out, int out_size, void* d_ws, size_t ws_size,
                              hipStream_t stream) {
  const float* x  = (const float*)d_in[0];
  const float* Wq = (const float*)d_in[1];
  const float* Wk = (const float*)d_in[2];
  const float* Wv = (const float*)d_in[3];
  const float* Wo = (const float*)d_in[4];

  char* ws = (char*)d_ws;
  f16* xb  = (f16*)(ws);                 // 8 MB (dead after gemm_qkv)
  f16* Wb  = (f16*)(ws + (8u << 20));    // 4 x 2 MB: Wq,Wk,Wv,Wo
  f16* Wqb = Wb;
  f16* Wkb = Wb + 1048576;
  f16* Wvb = Wb + 2097152;
  f16* Wob = Wb + 3145728;               // live until gemm_out
  f16* Qb  = (f16*)(ws + (16u << 20));   // 8 MB (pre-scaled by log2e/32)
  f16* Kb  = (f16*)(ws + (24u << 20));
  f16* Vtg = (f16*)(ws + (32u << 20));   // frag-layout V, 8 MB
  // split-K partials (overlaid on dead regions):
  f16*   Po0 = (f16*)(ws);                       // 8 MB over xb
  f16*   Po1 = (f16*)(ws + (40u << 20));         // 8 MB (old Ctx slot)
  float* Pl0 = (float*)(ws + (8u << 20));        // 256 KB over Wqb (dead)
  float* Pl1 = (float*)(ws + (8u << 20) + (256u << 10));
  f16*   Ctx = (f16*)(ws + (48u << 20));         // 8 MB -> peak 56 MB

  cast_all<<<8192, 256, 0, stream>>>(x, Wq, Wk, Wv, Wo, xb);

  gemm_qkv<<<dim3(24, 32), 256, 0, stream>>>(xb, Wqb, Wkb, Wvb, Qb, Kb, Vtg);
  attn_mfma<<<dim3(1024), 256, 0, stream>>>(Qb, Kb, Vtg, Po0, Po1, Pl0, Pl1);
  attn_combine<<<dim3(2048), 256, 0, stream>>>(Po0, Po1, Pl0, Pl1, Ctx);
  gemm_out<<<dim3(16, 32), 256, 0, stream>>>(Ctx, Wob, (float*)d_out);
}